// Round 1
// baseline (178.444 us; speedup 1.0000x reference)
//
#include <hip/hip_runtime.h>
#include <cstdint>
#include <cstddef>

// ---------------------------------------------------------------------------
// LSTM cell, B=8192, D=H=512, fp32 in/out.
// pre = [x|h] @ Wstack^T + bias ; gates -> c_t, h_t fused in GEMM epilogue.
// Round 4: 256x256 tile (grid 32x8 = 256 blocks = 1/CU), 8-phase schedule
// with counted vmcnt(8) (T3+T4), setprio around MFMA clusters (T5), XOR
// LDS swizzle kept (T2). 4 phases per K-tile of 64; stages 1 half-tile
// (16KB) per phase; prefetch distance 1 K-tile; vmcnt never drained to 0
// inside the main loop.
// ---------------------------------------------------------------------------

typedef __attribute__((ext_vector_type(8))) short short8;   // 8 bf16 = 4 VGPRs
typedef __attribute__((ext_vector_type(4))) float floatx4;  // MFMA acc

#define AS1(p) ((const __attribute__((address_space(1))) void*)(p))
#define AS3(p) ((__attribute__((address_space(3))) void*)(p))

__device__ __forceinline__ unsigned short f2bf(float f) {
  union { float f; unsigned u; } v; v.f = f;
  unsigned u = v.u;
  return (unsigned short)((u + 0x7fffu + ((u >> 16) & 1u)) >> 16);  // RNE
}

// --------------------------- pack everything -------------------------------
// blocks [0,8192):   A[b][k] = k<512 ? x[b][k] : h[b][k-512]      (8192x1024)
// blocks [8192,10240): B[n][k], n=gate*512+hh (f,i,g,o), k<512 -> Wx else Wh
//                      plus bias[n] = bx+bh at k==0.
struct PackArgs {
  const float* x; const float* h;
  const float* wx[4]; const float* wh[4];
  const float* bx[4]; const float* bh[4];
  unsigned short* A; unsigned short* B; float* bias;
};

__global__ __launch_bounds__(256) void pack_all_kernel(PackArgs P) {
  const int bid = blockIdx.x;
  if (bid < 8192) {
    int e = (bid * 256 + threadIdx.x) * 4;
    int b = e >> 10, k = e & 1023;
    const float* src = (k < 512) ? (P.x + b * 512 + k)
                                 : (P.h + b * 512 + (k - 512));
    float4 v = *(const float4*)src;
    ushort4 o;
    o.x = f2bf(v.x); o.y = f2bf(v.y); o.z = f2bf(v.z); o.w = f2bf(v.w);
    *(ushort4*)(P.A + e) = o;
  } else {
    int e = ((bid - 8192) * 256 + threadIdx.x) * 4;
    int n = e >> 10, k = e & 1023;
    int g = n >> 9, hh = n & 511;
    const float* src = (k < 512) ? (P.wx[g] + hh * 512 + k)
                                 : (P.wh[g] + hh * 512 + (k - 512));
    float4 v = *(const float4*)src;
    ushort4 o;
    o.x = f2bf(v.x); o.y = f2bf(v.y); o.z = f2bf(v.z); o.w = f2bf(v.w);
    *(ushort4*)(P.B + e) = o;
    if (k == 0) P.bias[n] = P.bx[g][hh] + P.bh[g][hh];
  }
}

// --------------------------- fused GEMM + LSTM epilogue --------------------
// Grid (32,8): tile = 256 batch x (4 gates x 64 hidden). K=1024, BK=64.
// 512 threads = 8 waves; wave grid 2M x 4N; wave tile 128x64 (one gate/wave).
// LDS (128 KiB): A = 2buf x 2khalf x [256 rows][64 B]   @ [0,65536)
//                B = 2buf x 2khalf x [256 rows][64 B]   @ [65536,131072)
// khalf-contiguous layout (row stride 64 B) so each global_load_lds half-tile
// stage is linear in LDS; 16B chunks swizzled chunk^= (row>>1)&3 (inverse
// swizzle applied on the GLOBAL source address, swizzle on the ds_read).

#define LDS4(dst, BASEOFF) do {                                   \
    dst[0] = *(const short8*)(smem + (BASEOFF));                  \
    dst[1] = *(const short8*)(smem + (BASEOFF) + 1024);           \
    dst[2] = *(const short8*)(smem + (BASEOFF) + 2048);           \
    dst[3] = *(const short8*)(smem + (BASEOFF) + 3072);           \
  } while (0)

#define MFMA16(MB) do {                                           \
    _Pragma("unroll")                                             \
    for (int i_ = 0; i_ < 4; ++i_)                                \
      _Pragma("unroll")                                           \
      for (int j_ = 0; j_ < 4; ++j_)                              \
        acc[(MB) + i_][j_] = __builtin_amdgcn_mfma_f32_16x16x32_bf16( \
            af[i_], bf[j_], acc[(MB) + i_][j_], 0, 0, 0);         \
  } while (0)

__global__ __launch_bounds__(512, 2)
void lstm_gemm_kernel(const unsigned short* __restrict__ A,   // [8192][1024]
                      const unsigned short* __restrict__ B,   // [2048][1024]
                      const float* __restrict__ bias,         // [2048]
                      const float* __restrict__ c_prev,       // [8192][512]
                      float* __restrict__ h_out,              // [8192][512]
                      float* __restrict__ c_out) {            // [8192][512]
  __shared__ __align__(16) char smem[131072];
  __shared__ float biasS[256];

  const int tid  = threadIdx.x;
  const int lane = tid & 63;
  const int w    = tid >> 6;        // wave 0..7
  const int quad = lane >> 4;
  const int colA = lane & 15;
  const int m0   = blockIdx.x * 256;
  const int h0   = blockIdx.y * 64;

  if (tid < 256) {
    // epilogue col c -> gate c>>6, hidden h0 + (c&63)
    biasS[tid] = bias[(tid >> 6) * 512 + h0 + (tid & 63)];
  }

  const int wm = (w >> 2) * 128;    // wave M offset (0 or 128)
  const int wn = (w & 3) * 64;      // wave N offset = gate*64 region

  // LDS read offsets within one [256][64B] khalf section
  const int swzR = (quad ^ ((colA >> 1) & 3)) * 16;
  const int rdA  = (wm + colA) * 64 + swzR;              // + mi*1024
  const int rdB  = (wn + colA) * 64 + swzR;              // + ni*1024

  // staging geometry: chunk c = w*128 + l*64 + lane; row = c>>2, pos = lane&3
  const int lrow   = lane >> 2;                          // 0..15
  const int swzS   = ((lane & 3) ^ ((lane >> 3) & 3)) * 16;  // inverse swz on src
  const int sgArow = m0 + w * 32 + lrow;                 // + l*16
  const int growB0 = ((2 * w + 0) >> 2) * 512 + h0 + ((w * 32) & 63) + lrow;
  const int growB1 = ((2 * w + 1) >> 2) * 512 + h0 + ((w * 32 + 16) & 63) + lrow;
  const int ldsStage = w * 2048 + lane * 16;             // + l*1024

  const char* Ag = (const char*)A;
  const char* Bg = (const char*)B;

  floatx4 acc[8][4];
#pragma unroll
  for (int i = 0; i < 8; ++i)
#pragma unroll
    for (int j = 0; j < 4; ++j) acc[i][j] = (floatx4){0.f, 0.f, 0.f, 0.f};

  // stage one A khalf (256 rows x 32 k) of tile ktt into buffer bb
  auto stageA = [&](int ktt, int kh, int bb) {
    const int kb = (ktt & 15) * 128 + kh * 64;
#pragma unroll
    for (int l = 0; l < 2; ++l)
      __builtin_amdgcn_global_load_lds(
          AS1(Ag + (size_t)(sgArow + l * 16) * 2048 + kb + swzS),
          AS3(smem + bb * 32768 + kh * 16384 + ldsStage + l * 1024), 16, 0, 0);
  };
  auto stageB = [&](int ktt, int kh, int bb) {
    const int kb = (ktt & 15) * 128 + kh * 64;
    __builtin_amdgcn_global_load_lds(
        AS1(Bg + (size_t)growB0 * 2048 + kb + swzS),
        AS3(smem + 65536 + bb * 32768 + kh * 16384 + ldsStage), 16, 0, 0);
    __builtin_amdgcn_global_load_lds(
        AS1(Bg + (size_t)growB1 * 2048 + kb + swzS),
        AS3(smem + 65536 + bb * 32768 + kh * 16384 + ldsStage + 1024), 16, 0, 0);
  };

  // ---- prologue: tile 0 fully + first halves of tile 1 (6 stages) ----
  stageA(0, 0, 0); stageB(0, 0, 0);
  stageA(0, 1, 0); stageB(0, 1, 0);
  stageA(1, 0, 1); stageB(1, 0, 1);
  asm volatile("s_waitcnt vmcnt(8)" ::: "memory");   // tile0 kh0 (A+B) landed
  __builtin_amdgcn_s_barrier();
  asm volatile("" ::: "memory");

  short8 af[4], bf[4];

  for (int kt = 0; kt < 16; ++kt) {
    const int buf = kt & 1;
    const int bA  = buf * 32768;
    const int bB  = 65536 + buf * 32768;

    // ---- phase 1: kk=0, mi 0-3 (+ B kk0) | stage A(kt+1) kh1 ----
    LDS4(af, bA + rdA);
    LDS4(bf, bB + rdB);
    stageA(kt + 1, 1, buf ^ 1);
    __builtin_amdgcn_s_barrier();
    asm volatile("s_waitcnt lgkmcnt(0)" ::: "memory");
    __builtin_amdgcn_s_setprio(1);
    MFMA16(0);
    __builtin_amdgcn_s_setprio(0);
    __builtin_amdgcn_s_barrier();

    // ---- phase 2: kk=0, mi 4-7 | stage B(kt+1) kh1 | wait kh1(kt) ----
    LDS4(af, bA + rdA + 4096);
    stageB(kt + 1, 1, buf ^ 1);
    __builtin_amdgcn_s_barrier();
    asm volatile("s_waitcnt lgkmcnt(0)" ::: "memory");
    __builtin_amdgcn_s_setprio(1);
    MFMA16(4);
    __builtin_amdgcn_s_setprio(0);
    asm volatile("s_waitcnt vmcnt(8)" ::: "memory");   // A/B(kt) kh1 landed
    __builtin_amdgcn_s_barrier();
    asm volatile("" ::: "memory");

    // ---- phase 3: kk=1, mi 0-3 (+ B kk1) | stage A(kt+2) kh0 ----
    LDS4(af, bA + 16384 + rdA);
    LDS4(bf, bB + 16384 + rdB);
    stageA(kt + 2, 0, buf);
    __builtin_amdgcn_s_barrier();
    asm volatile("s_waitcnt lgkmcnt(0)" ::: "memory");
    __builtin_amdgcn_s_setprio(1);
    MFMA16(0);
    __builtin_amdgcn_s_setprio(0);
    __builtin_amdgcn_s_barrier();

    // ---- phase 4: kk=1, mi 4-7 | stage B(kt+2) kh0 | wait kh0(kt+1) ----
    LDS4(af, bA + 16384 + rdA + 4096);
    stageB(kt + 2, 0, buf);
    __builtin_amdgcn_s_barrier();
    asm volatile("s_waitcnt lgkmcnt(0)" ::: "memory");
    __builtin_amdgcn_s_setprio(1);
    MFMA16(4);
    __builtin_amdgcn_s_setprio(0);
    asm volatile("s_waitcnt vmcnt(8)" ::: "memory");   // A/B(kt+1) kh0 landed
    __builtin_amdgcn_s_barrier();
    asm volatile("" ::: "memory");
  }

  // drain the wrap-around tail stages before overlaying LDS with epilogue
  asm volatile("s_waitcnt vmcnt(0)" ::: "memory");
  __syncthreads();

  // ------------------- fused epilogue (4 rounds of 64 M-rows) --------------
  float* ep = (float*)smem;         // [64][258] fp32, overlays A/B buffers
  const int gate = w & 3;
#pragma unroll
  for (int rd = 0; rd < 4; ++rd) {
    if ((w >> 2) == (rd >> 1)) {    // the 4 waves whose wm-half covers rd
      const int mib = (rd & 1) * 4;
#pragma unroll
      for (int mi2 = 0; mi2 < 4; ++mi2)
#pragma unroll
        for (int ni = 0; ni < 4; ++ni) {
          int rr0 = mi2 * 16 + quad * 4;                // local row 0..63
          int cc  = gate * 64 + ni * 16 + colA;         // col 0..255
#pragma unroll
          for (int rr = 0; rr < 4; ++rr)
            ep[(rr0 + rr) * 258 + cc] = acc[mib + mi2][ni][rr];
        }
    }
    __syncthreads();
#pragma unroll
    for (int j = 0; j < 8; ++j) {
      int idx  = j * 512 + tid;     // 0..4095
      int mloc = idx >> 6;
      int hh   = idx & 63;
      float pf = ep[mloc * 258 +       hh] + biasS[hh];
      float pi = ep[mloc * 258 +  64 + hh] + biasS[64 + hh];
      float pg = ep[mloc * 258 + 128 + hh] + biasS[128 + hh];
      float po = ep[mloc * 258 + 192 + hh] + biasS[192 + hh];
      float fg = 1.f / (1.f + __expf(-pf));
      float ig = 1.f / (1.f + __expf(-pi));
      float gg = 1.f - 2.f / (1.f + __expf(2.f * pg));
      float og = 1.f / (1.f + __expf(-po));
      int m  = m0 + rd * 64 + mloc;
      int hg = h0 + hh;
      float cp = c_prev[m * 512 + hg];
      float cv = fg * cp + ig * gg;
      float th = 1.f - 2.f / (1.f + __expf(2.f * cv));
      h_out[m * 512 + hg] = og * th;
      c_out[m * 512 + hg] = cv;
    }
    __syncthreads();
  }
}

// ---------------------------------------------------------------------------
extern "C" void kernel_launch(void* const* d_in, const int* in_sizes, int n_in,
                              void* d_out, int out_size, void* d_ws, size_t ws_size,
                              hipStream_t stream) {
  // workspace: A_bf16 (16 MiB) | B_bf16 (4 MiB) | bias (8 KiB)
  char* ws = (char*)d_ws;
  unsigned short* Abf = (unsigned short*)ws;
  unsigned short* Bbf = (unsigned short*)(ws + (size_t)16777216);
  float* bias = (float*)(ws + (size_t)16777216 + 4194304);

  float* hout = (float*)d_out;
  float* cout = hout + (size_t)8192 * 512;

  PackArgs P;
  P.x = (const float*)d_in[0];
  P.h = (const float*)d_in[1];
  // gate order in stacked B: 0=f, 1=i, 2=g(cell), 3=o
  P.wx[0] = (const float*)d_in[3];  P.bx[0] = (const float*)d_in[4];
  P.wh[0] = (const float*)d_in[5];  P.bh[0] = (const float*)d_in[6];
  P.wx[1] = (const float*)d_in[7];  P.bx[1] = (const float*)d_in[8];
  P.wh[1] = (const float*)d_in[9];  P.bh[1] = (const float*)d_in[10];
  P.wx[2] = (const float*)d_in[11]; P.bx[2] = (const float*)d_in[12];
  P.wh[2] = (const float*)d_in[13]; P.bh[2] = (const float*)d_in[14];
  P.wx[3] = (const float*)d_in[15]; P.bx[3] = (const float*)d_in[16];
  P.wh[3] = (const float*)d_in[17]; P.bh[3] = (const float*)d_in[18];
  P.A = Abf; P.B = Bbf; P.bias = bias;

  pack_all_kernel<<<10240, 256, 0, stream>>>(P);

  const float* c = (const float*)d_in[2];
  dim3 grid(32, 8);
  lstm_gemm_kernel<<<grid, 512, 0, stream>>>(Abf, Bbf, bias, c, hout, cout);
}

// Round 2
// 173.944 us; speedup vs baseline: 1.0259x; 1.0259x over previous
//
#include <hip/hip_runtime.h>
#include <cstdint>
#include <cstddef>

// ---------------------------------------------------------------------------
// LSTM cell, B=8192, D=H=512, fp32 in/out.
// pre = [x|h] @ Wstack^T + bias ; gates -> c_t, h_t fused in GEMM epilogue.
// Round 5: faithful m201-style 8-phase port. 256x256 tile, BK=64, 8 waves.
// M-half LDS layout with 128-B rows + r3's PROVEN zero-conflict XOR swizzle
// (chunk ^= row&7, inverse on global source). Quadrant order gives read
// pattern 12,4,8,0 per K-tile; stage queue {B1,A1,B0,A0} derived from
// last-read constraints; ONE vmcnt(4) per K-tile at Ph4-end (2 half-tiles
// in flight, min 2.5-phase lead). setprio(1) around each 16-MFMA cluster.
// ---------------------------------------------------------------------------

typedef __attribute__((ext_vector_type(8))) short short8;   // 8 bf16 = 4 VGPRs
typedef __attribute__((ext_vector_type(4))) float floatx4;  // MFMA acc

#define AS1(p) ((const __attribute__((address_space(1))) void*)(p))
#define AS3(p) ((__attribute__((address_space(3))) void*)(p))

__device__ __forceinline__ unsigned short f2bf(float f) {
  union { float f; unsigned u; } v; v.f = f;
  unsigned u = v.u;
  return (unsigned short)((u + 0x7fffu + ((u >> 16) & 1u)) >> 16);  // RNE
}

// --------------------------- pack everything -------------------------------
struct PackArgs {
  const float* x; const float* h;
  const float* wx[4]; const float* wh[4];
  const float* bx[4]; const float* bh[4];
  unsigned short* A; unsigned short* B; float* bias;
};

__global__ __launch_bounds__(256) void pack_all_kernel(PackArgs P) {
  const int bid = blockIdx.x;
  if (bid < 8192) {
    int e = (bid * 256 + threadIdx.x) * 4;
    int b = e >> 10, k = e & 1023;
    const float* src = (k < 512) ? (P.x + b * 512 + k)
                                 : (P.h + b * 512 + (k - 512));
    float4 v = *(const float4*)src;
    ushort4 o;
    o.x = f2bf(v.x); o.y = f2bf(v.y); o.z = f2bf(v.z); o.w = f2bf(v.w);
    *(ushort4*)(P.A + e) = o;
  } else {
    int e = ((bid - 8192) * 256 + threadIdx.x) * 4;
    int n = e >> 10, k = e & 1023;
    int g = n >> 9, hh = n & 511;
    const float* src = (k < 512) ? (P.wx[g] + hh * 512 + k)
                                 : (P.wh[g] + hh * 512 + (k - 512));
    float4 v = *(const float4*)src;
    ushort4 o;
    o.x = f2bf(v.x); o.y = f2bf(v.y); o.z = f2bf(v.z); o.w = f2bf(v.w);
    *(ushort4*)(P.B + e) = o;
    if (k == 0) P.bias[n] = P.bx[g][hh] + P.bh[g][hh];
  }
}

// --------------------------- fused GEMM + LSTM epilogue --------------------
// Grid (32,8): tile = 256 batch x (4 gates x 64 hidden). K=1024, 16 K-tiles.
// 8 waves = 2M x 4N; wave tile 128x64 (one gate per wave).
// LDS 128 KiB: A = 2buf x [256 rows][128 B] @ 0; B = same @ 65536.
// Half-tile = 128 rows x 128 B = 16 KB = 2 global_load_lds per thread.
// Swizzle: 16-B chunk c of row r stored at chunk c ^ (r&7) (r3-proven).

#define MFMA_Q(MB, NB, AF, BF) do {                                    \
    _Pragma("unroll")                                                  \
    for (int mi_ = 0; mi_ < 4; ++mi_)                                  \
      _Pragma("unroll")                                                \
      for (int ni_ = 0; ni_ < 2; ++ni_)                                \
        _Pragma("unroll")                                              \
        for (int kk_ = 0; kk_ < 2; ++kk_)                              \
          acc[(MB) + mi_][(NB) + ni_] =                                \
              __builtin_amdgcn_mfma_f32_16x16x32_bf16(                 \
                  AF[mi_][kk_], BF[ni_][kk_],                          \
                  acc[(MB) + mi_][(NB) + ni_], 0, 0, 0);               \
  } while (0)

__global__ __launch_bounds__(512, 2)
void lstm_gemm_kernel(const unsigned short* __restrict__ A,   // [8192][1024]
                      const unsigned short* __restrict__ B,   // [2048][1024]
                      const float* __restrict__ bias,         // [2048]
                      const float* __restrict__ c_prev,       // [8192][512]
                      float* __restrict__ h_out,              // [8192][512]
                      float* __restrict__ c_out) {            // [8192][512]
  __shared__ __align__(16) char smem[131072];
  __shared__ float biasS[256];

  const int tid  = threadIdx.x;
  const int lane = tid & 63;
  const int w    = tid >> 6;        // wave 0..7
  const int quad = lane >> 4;
  const int colA = lane & 15;
  const int m0   = blockIdx.x * 256;
  const int h0   = blockIdx.y * 64;

  if (tid < 256) {
    // epilogue col c -> gate c>>6, hidden h0 + (c&63)
    biasS[tid] = bias[(tid >> 6) * 512 + h0 + (tid & 63)];
  }

  const int wm = (w >> 2) * 128;    // wave M offset (0 or 128)
  const int wn = (w & 3) * 64;      // wave N offset = gate*64

  // fragment read offsets: row = wm/wn + i*16 + colA (row&7 == colA&7),
  // global chunk q = kk*4+quad stored at q ^ (colA&7)
  const int swz0 = (quad ^ (colA & 7)) * 16;
  const int swz1 = swz0 ^ 64;                 // (4+quad) ^ c7, in bytes
  const int aOff = (wm + colA) * 128;
  const int bOff = (wn + colA) * 128;

  // staging: per load instr, thread covers row l*64 + (tid>>3), chunk tid&7;
  // global source chunk = (tid&7) ^ (row&7) so LDS holds the swizzled layout
  const int sRow   = tid >> 3;                               // 0..63
  const int srcswz = ((tid & 7) ^ ((tid >> 3) & 7)) * 16;
  const int ldsOff = tid * 16;                               // linear dest

  const char* Ag = (const char*)A;
  const char* Bg = (const char*)B;

  floatx4 acc[8][4];
#pragma unroll
  for (int i = 0; i < 8; ++i)
#pragma unroll
    for (int j = 0; j < 4; ++j) acc[i][j] = (floatx4){0.f, 0.f, 0.f, 0.f};

  auto stageA = [&](int ktt, int hh) {     // A half-tile: rows hh*128..+127
    const int kb = (ktt & 15) * 128;
    const int db = (ktt & 1) * 32768 + hh * 16384 + ldsOff;
#pragma unroll
    for (int l = 0; l < 2; ++l)
      __builtin_amdgcn_global_load_lds(
          AS1(Ag + (size_t)(m0 + hh * 128 + l * 64 + sRow) * 2048 + kb + srcswz),
          AS3(smem + db + l * 8192), 16, 0, 0);
  };
  auto stageB = [&](int ktt, int hh) {     // B half-tile: gates 2hh, 2hh+1
    const int kb = (ktt & 15) * 128;
    const int db = 65536 + (ktt & 1) * 32768 + hh * 16384 + ldsOff;
#pragma unroll
    for (int l = 0; l < 2; ++l)
      __builtin_amdgcn_global_load_lds(
          AS1(Bg + (size_t)((2 * hh + l) * 512 + h0 + sRow) * 2048 + kb + srcswz),
          AS3(smem + db + l * 8192), 16, 0, 0);
  };

  // ---- prologue: queue order = steady-state queue ----
  // t0.B0, t0.A0, t0.B1, t0.A1, t1.B0, t1.A0  (12 loads)
  stageB(0, 0); stageA(0, 0); stageB(0, 1); stageA(0, 1);
  stageB(1, 0); stageA(1, 0);
  asm volatile("s_waitcnt vmcnt(4)" ::: "memory");   // t0 fully landed
  __builtin_amdgcn_s_barrier();

  short8 af[4][2], bf[2][2], bf2[2][2];

  for (int kt = 0; kt < 16; ++kt) {
    const int bA = (kt & 1) * 32768;
    const int bB = 65536 + (kt & 1) * 32768;

    // ---- Ph1: Q1 = mi0-3 x ni0-1 (12 reads) | stage (kt+1).B1 ----
#pragma unroll
    for (int mi = 0; mi < 4; ++mi) {
      af[mi][0] = *(const short8*)(smem + bA + aOff + mi * 2048 + swz0);
      af[mi][1] = *(const short8*)(smem + bA + aOff + mi * 2048 + swz1);
    }
#pragma unroll
    for (int ni = 0; ni < 2; ++ni) {
      bf[ni][0] = *(const short8*)(smem + bB + bOff + ni * 2048 + swz0);
      bf[ni][1] = *(const short8*)(smem + bB + bOff + ni * 2048 + swz1);
    }
    stageB(kt + 1, 1);
    asm volatile("s_waitcnt lgkmcnt(8)" ::: "memory");
    __builtin_amdgcn_s_barrier();
    asm volatile("s_waitcnt lgkmcnt(0)" ::: "memory");
    __builtin_amdgcn_s_setprio(1);
    MFMA_Q(0, 0, af, bf);
    __builtin_amdgcn_s_setprio(0);
    __builtin_amdgcn_s_barrier();

    // ---- Ph2: Q2 = mi0-3 x ni2-3 (4 reads) | stage (kt+1).A1 ----
#pragma unroll
    for (int ni = 0; ni < 2; ++ni) {
      bf2[ni][0] = *(const short8*)(smem + bB + bOff + (ni + 2) * 2048 + swz0);
      bf2[ni][1] = *(const short8*)(smem + bB + bOff + (ni + 2) * 2048 + swz1);
    }
    stageA(kt + 1, 1);
    __builtin_amdgcn_s_barrier();
    asm volatile("s_waitcnt lgkmcnt(0)" ::: "memory");
    __builtin_amdgcn_s_setprio(1);
    MFMA_Q(0, 2, af, bf2);
    __builtin_amdgcn_s_setprio(0);
    __builtin_amdgcn_s_barrier();

    // ---- Ph3: Q3 = mi4-7 x ni2-3 (8 reads, af reload) | stage (kt+2).B0 ----
#pragma unroll
    for (int mi = 0; mi < 4; ++mi) {
      af[mi][0] = *(const short8*)(smem + bA + aOff + (mi + 4) * 2048 + swz0);
      af[mi][1] = *(const short8*)(smem + bA + aOff + (mi + 4) * 2048 + swz1);
    }
    stageB(kt + 2, 0);
    __builtin_amdgcn_s_barrier();
    asm volatile("s_waitcnt lgkmcnt(0)" ::: "memory");
    __builtin_amdgcn_s_setprio(1);
    MFMA_Q(4, 2, af, bf2);
    __builtin_amdgcn_s_setprio(0);
    __builtin_amdgcn_s_barrier();

    // ---- Ph4: Q4 = mi4-7 x ni0-1 (0 reads) | stage (kt+2).A0 | vmcnt(4) ----
    stageA(kt + 2, 0);
    __builtin_amdgcn_s_barrier();
    __builtin_amdgcn_s_setprio(1);
    MFMA_Q(4, 0, af, bf);
    __builtin_amdgcn_s_setprio(0);
    asm volatile("s_waitcnt vmcnt(4)" ::: "memory");   // tile kt+1 landed
    __builtin_amdgcn_s_barrier();
  }

  // drain wrap-around tail stages before overlaying LDS with the epilogue
  asm volatile("s_waitcnt vmcnt(0)" ::: "memory");
  __syncthreads();

  // ------------------- fused epilogue (4 rounds of 64 M-rows) --------------
  float* ep = (float*)smem;         // [64][258] fp32 overlay
  const int gate = w & 3;
#pragma unroll
  for (int rd = 0; rd < 4; ++rd) {
    if ((w >> 2) == (rd >> 1)) {    // the 4 waves whose wm-half covers rd
      const int mib = (rd & 1) * 4;
#pragma unroll
      for (int mi2 = 0; mi2 < 4; ++mi2)
#pragma unroll
        for (int ni = 0; ni < 4; ++ni) {
          int rr0 = mi2 * 16 + quad * 4;                // local row 0..63
          int cc  = gate * 64 + ni * 16 + colA;         // col 0..255
#pragma unroll
          for (int rr = 0; rr < 4; ++rr)
            ep[(rr0 + rr) * 258 + cc] = acc[mib + mi2][ni][rr];
        }
    }
    __syncthreads();
#pragma unroll
    for (int j = 0; j < 8; ++j) {
      int idx  = j * 512 + tid;     // 0..4095
      int mloc = idx >> 6;
      int hh   = idx & 63;
      float pf = ep[mloc * 258 +       hh] + biasS[hh];
      float pi = ep[mloc * 258 +  64 + hh] + biasS[64 + hh];
      float pg = ep[mloc * 258 + 128 + hh] + biasS[128 + hh];
      float po = ep[mloc * 258 + 192 + hh] + biasS[192 + hh];
      float fg = 1.f / (1.f + __expf(-pf));
      float ig = 1.f / (1.f + __expf(-pi));
      float gg = 1.f - 2.f / (1.f + __expf(2.f * pg));
      float og = 1.f / (1.f + __expf(-po));
      int m  = m0 + rd * 64 + mloc;
      int hg = h0 + hh;
      float cp = c_prev[m * 512 + hg];
      float cv = fg * cp + ig * gg;
      float th = 1.f - 2.f / (1.f + __expf(2.f * cv));
      h_out[m * 512 + hg] = og * th;
      c_out[m * 512 + hg] = cv;
    }
    __syncthreads();
  }
}

// ---------------------------------------------------------------------------
extern "C" void kernel_launch(void* const* d_in, const int* in_sizes, int n_in,
                              void* d_out, int out_size, void* d_ws, size_t ws_size,
                              hipStream_t stream) {
  // workspace: A_bf16 (16 MiB) | B_bf16 (4 MiB) | bias (8 KiB)
  char* ws = (char*)d_ws;
  unsigned short* Abf = (unsigned short*)ws;
  unsigned short* Bbf = (unsigned short*)(ws + (size_t)16777216);
  float* bias = (float*)(ws + (size_t)16777216 + 4194304);

  float* hout = (float*)d_out;
  float* cout = hout + (size_t)8192 * 512;

  PackArgs P;
  P.x = (const float*)d_in[0];
  P.h = (const float*)d_in[1];
  // gate order in stacked B: 0=f, 1=i, 2=g(cell), 3=o
  P.wx[0] = (const float*)d_in[3];  P.bx[0] = (const float*)d_in[4];
  P.wh[0] = (const float*)d_in[5];  P.bh[0] = (const float*)d_in[6];
  P.wx[1] = (const float*)d_in[7];  P.bx[1] = (const float*)d_in[8];
  P.wh[1] = (const float*)d_in[9];  P.bh[1] = (const float*)d_in[10];
  P.wx[2] = (const float*)d_in[11]; P.bx[2] = (const float*)d_in[12];
  P.wh[2] = (const float*)d_in[13]; P.bh[2] = (const float*)d_in[14];
  P.wx[3] = (const float*)d_in[15]; P.bx[3] = (const float*)d_in[16];
  P.wh[3] = (const float*)d_in[17]; P.bh[3] = (const float*)d_in[18];
  P.A = Abf; P.B = Bbf; P.bias = bias;

  pack_all_kernel<<<10240, 256, 0, stream>>>(P);

  const float* c = (const float*)d_in[2];
  dim3 grid(32, 8);
  lstm_gemm_kernel<<<grid, 512, 0, stream>>>(Abf, Bbf, bias, c, hout, cout);
}

// Round 3
// 170.363 us; speedup vs baseline: 1.0474x; 1.0210x over previous
//
#include <hip/hip_runtime.h>
#include <cstdint>
#include <cstddef>

// ---------------------------------------------------------------------------
// LSTM cell, B=8192, D=H=512, fp32 in/out.
// pre = [x|h] @ Wstack^T + bias ; gates -> c_t, h_t fused in GEMM epilogue.
// Round 6: m97-replica. 128x128 tile, BK=64, 256 thr (4 waves, 64x64 wave
// tile), single-buffered 32KB LDS, plain sync;stage;sync;compute K-loop.
// ~34KB LDS + <=128 VGPR -> 4 blocks/CU (grid 64x16 = 1024 = all resident).
// Cross-block TLP is the stall-hiding mechanism (m97: 912 TF), replacing
// the failed 8-phase attempts (r4/r5: 1 blk/CU, lockstep stalls).
// B packed h-interleaved (row n = h*4+gate) so a 128-col tile holds all 4
// gates for 32 hidden units -> LSTM epilogue fuses in-block, reading each
// cell's (f,i,g,o) as one float4 from LDS. Epilogue stride 132 (4 rows ==
// 16 mod 32 banks -> conflict-free; r4/r5's 258 cost 524288 conflict cyc).
// ---------------------------------------------------------------------------

typedef __attribute__((ext_vector_type(8))) short short8;   // 8 bf16 = 4 VGPRs
typedef __attribute__((ext_vector_type(4))) float floatx4;  // MFMA acc

#define AS1(p) ((const __attribute__((address_space(1))) void*)(p))
#define AS3(p) ((__attribute__((address_space(3))) void*)(p))

__device__ __forceinline__ unsigned short f2bf(float f) {
  union { float f; unsigned u; } v; v.f = f;
  unsigned u = v.u;
  return (unsigned short)((u + 0x7fffu + ((u >> 16) & 1u)) >> 16);  // RNE
}

// --------------------------- pack everything -------------------------------
// blocks [0,8192):    A[b][k] = k<512 ? x[b][k] : h[b][k-512]     (8192x1024)
// blocks [8192,10240): B[n][k], n = hh*4 + g  (h-interleaved gates, g order
//                      f,i,g,o), k<512 -> Wx else Wh; bias[n] = bx+bh @ k==0.
struct PackArgs {
  const float* x; const float* h;
  const float* wx[4]; const float* wh[4];
  const float* bx[4]; const float* bh[4];
  unsigned short* A; unsigned short* B; float* bias;
};

__global__ __launch_bounds__(256) void pack_all_kernel(PackArgs P) {
  const int bid = blockIdx.x;
  if (bid < 8192) {
    int e = (bid * 256 + threadIdx.x) * 4;
    int b = e >> 10, k = e & 1023;
    const float* src = (k < 512) ? (P.x + b * 512 + k)
                                 : (P.h + b * 512 + (k - 512));
    float4 v = *(const float4*)src;
    ushort4 o;
    o.x = f2bf(v.x); o.y = f2bf(v.y); o.z = f2bf(v.z); o.w = f2bf(v.w);
    *(ushort4*)(P.A + e) = o;
  } else {
    int e = ((bid - 8192) * 256 + threadIdx.x) * 4;
    int n = e >> 10, k = e & 1023;
    int g = n & 3, hh = n >> 2;                 // h-interleaved layout
    const float* src = (k < 512) ? (P.wx[g] + hh * 512 + k)
                                 : (P.wh[g] + hh * 512 + (k - 512));
    float4 v = *(const float4*)src;
    ushort4 o;
    o.x = f2bf(v.x); o.y = f2bf(v.y); o.z = f2bf(v.z); o.w = f2bf(v.w);
    *(ushort4*)(P.B + e) = o;
    if (k == 0) P.bias[n] = P.bx[g][hh] + P.bh[g][hh];
  }
}

// --------------------------- fused GEMM + LSTM epilogue --------------------
// Grid (64,16): tile = 128 batch x 128 cols (32 hidden x 4 gates). K=1024,
// BK=64 (16 steps). 256 threads = 4 waves (2M x 2N), wave tile 64x64.
// LDS: As [128][128B] @0 (16KB), Bs @16384 (16KB); epilogue ep[64][132] f32
// (33792 B) overlays both. XOR swizzle: 16B chunk c of row r at c^(r&7),
// inverse applied on the global source address (r3-proven, 0 conflicts).
__global__ __launch_bounds__(256, 4)
void lstm_gemm_kernel(const unsigned short* __restrict__ A,   // [8192][1024]
                      const unsigned short* __restrict__ B,   // [2048][1024]
                      const float* __restrict__ bias,         // [2048]
                      const float* __restrict__ c_prev,       // [8192][512]
                      float* __restrict__ h_out,              // [8192][512]
                      float* __restrict__ c_out) {            // [8192][512]
  __shared__ __align__(16) char smem[33792];
  __shared__ __align__(16) float biasS[128];

  const int tid  = threadIdx.x;
  const int lane = tid & 63;
  const int w    = tid >> 6;        // wave 0..3
  const int quad = lane >> 4;
  const int colA = lane & 15;
  const int m0   = blockIdx.x * 128;
  const int n0   = blockIdx.y * 128;    // = h0*4, h0 = blockIdx.y*32
  const int h0   = blockIdx.y * 32;

  if (tid < 128) biasS[tid] = bias[n0 + tid];   // contiguous in h-interleave

  const int wm = (w >> 1) * 64;     // wave M offset (0 or 64)
  const int wn = (w & 1) * 64;      // wave N offset (0 or 64)

  // staging: thread covers tile-row r = j*32 + (tid>>3), 16B chunk (tid&7);
  // global chunk XOR'd by row&7 so LDS holds the swizzled layout
  const int srow = tid >> 3;        // 0..31
  const int cl   = tid & 7;
  const int cg   = cl ^ (srow & 7);

  floatx4 acc[4][4];
#pragma unroll
  for (int i = 0; i < 4; ++i)
#pragma unroll
    for (int j = 0; j < 4; ++j) acc[i][j] = (floatx4){0.f, 0.f, 0.f, 0.f};

  const char* Ag = (const char*)A;
  const char* Bg = (const char*)B;

  for (int kt = 0; kt < 16; ++kt) {
    __syncthreads();                // prior LDS reads done
    const int kb = kt * 128;        // byte offset into 2048-B rows
#pragma unroll
    for (int j = 0; j < 4; ++j) {   // A: 128 rows
      int r = j * 32 + srow;        // r&7 == srow&7
      __builtin_amdgcn_global_load_lds(
          AS1(Ag + (size_t)(m0 + r) * 2048 + kb + cg * 16),
          AS3(smem + r * 128 + cl * 16), 16, 0, 0);
    }
#pragma unroll
    for (int j = 0; j < 4; ++j) {   // B: 128 rows (h-interleaved)
      int r = j * 32 + srow;
      __builtin_amdgcn_global_load_lds(
          AS1(Bg + (size_t)(n0 + r) * 2048 + kb + cg * 16),
          AS3(smem + 16384 + r * 128 + cl * 16), 16, 0, 0);
    }
    __syncthreads();                // compiler drains vmcnt(0) here (m97)

#pragma unroll
    for (int kk = 0; kk < 2; ++kk) {
      const int off = ((kk * 4 + quad) ^ (colA & 7)) * 16;
      short8 af[4], bfr[4];
#pragma unroll
      for (int mi = 0; mi < 4; ++mi)
        af[mi] = *(const short8*)(smem + (wm + mi * 16 + colA) * 128 + off);
#pragma unroll
      for (int ni = 0; ni < 4; ++ni)
        bfr[ni] = *(const short8*)(smem + 16384 + (wn + ni * 16 + colA) * 128 + off);
#pragma unroll
      for (int mi = 0; mi < 4; ++mi)
#pragma unroll
        for (int ni = 0; ni < 4; ++ni)
          acc[mi][ni] = __builtin_amdgcn_mfma_f32_16x16x32_bf16(
              af[mi], bfr[ni], acc[mi][ni], 0, 0, 0);
    }
  }

  // ------------------- fused epilogue (2 rounds of 64 M-rows) --------------
  __syncthreads();
  float* ep = (float*)smem;         // [64][132] fp32, conflict-free stride
#pragma unroll
  for (int rd = 0; rd < 2; ++rd) {
    // issue c_prev loads early; latency hides under ep writes + barrier
    float cp[8];
#pragma unroll
    for (int j = 0; j < 8; ++j) {
      int idx  = j * 256 + tid;     // 0..2047
      int mloc = idx >> 5;
      int hh   = idx & 31;
      cp[j] = c_prev[(m0 + rd * 64 + mloc) * 512 + h0 + hh];
    }
    if ((w >> 1) == rd) {           // the 2 waves with wm == rd*64
      // C/D layout: row = quad*4 + rr, col = lane&15
#pragma unroll
      for (int mi = 0; mi < 4; ++mi)
#pragma unroll
        for (int ni = 0; ni < 4; ++ni) {
          int rr0 = mi * 16 + quad * 4;                 // local row 0..63
          int cc  = wn + ni * 16 + colA;                // col 0..127
#pragma unroll
          for (int rr = 0; rr < 4; ++rr)
            ep[(rr0 + rr) * 132 + cc] = acc[mi][ni][rr];
        }
    }
    __syncthreads();
#pragma unroll
    for (int j = 0; j < 8; ++j) {
      int idx  = j * 256 + tid;     // 0..2047
      int mloc = idx >> 5;
      int hh   = idx & 31;
      // one aligned float4 = (f,i,g,o) pre-activations for this (m,h)
      float4 pre = *(const float4*)(ep + mloc * 132 + hh * 4);
      float4 bb  = *(const float4*)(biasS + hh * 4);
      float pf = pre.x + bb.x;
      float pi = pre.y + bb.y;
      float pg = pre.z + bb.z;
      float po = pre.w + bb.w;
      float fg = 1.f / (1.f + __expf(-pf));
      float ig = 1.f / (1.f + __expf(-pi));
      float gg = 1.f - 2.f / (1.f + __expf(2.f * pg));
      float og = 1.f / (1.f + __expf(-po));
      float cv = fg * cp[j] + ig * gg;
      float th = 1.f - 2.f / (1.f + __expf(2.f * cv));
      int m  = m0 + rd * 64 + mloc;
      int hg = h0 + hh;
      h_out[m * 512 + hg] = og * th;
      c_out[m * 512 + hg] = cv;
    }
    __syncthreads();
  }
}

// ---------------------------------------------------------------------------
extern "C" void kernel_launch(void* const* d_in, const int* in_sizes, int n_in,
                              void* d_out, int out_size, void* d_ws, size_t ws_size,
                              hipStream_t stream) {
  // workspace: A_bf16 (16 MiB) | B_bf16 (4 MiB) | bias (8 KiB)
  char* ws = (char*)d_ws;
  unsigned short* Abf = (unsigned short*)ws;
  unsigned short* Bbf = (unsigned short*)(ws + (size_t)16777216);
  float* bias = (float*)(ws + (size_t)16777216 + 4194304);

  float* hout = (float*)d_out;
  float* cout = hout + (size_t)8192 * 512;

  PackArgs P;
  P.x = (const float*)d_in[0];
  P.h = (const float*)d_in[1];
  // gate order: 0=f, 1=i, 2=g(cell), 3=o
  P.wx[0] = (const float*)d_in[3];  P.bx[0] = (const float*)d_in[4];
  P.wh[0] = (const float*)d_in[5];  P.bh[0] = (const float*)d_in[6];
  P.wx[1] = (const float*)d_in[7];  P.bx[1] = (const float*)d_in[8];
  P.wh[1] = (const float*)d_in[9];  P.bh[1] = (const float*)d_in[10];
  P.wx[2] = (const float*)d_in[11]; P.bx[2] = (const float*)d_in[12];
  P.wh[2] = (const float*)d_in[13]; P.bh[2] = (const float*)d_in[14];
  P.wx[3] = (const float*)d_in[15]; P.bx[3] = (const float*)d_in[16];
  P.wh[3] = (const float*)d_in[17]; P.bh[3] = (const float*)d_in[18];
  P.A = Abf; P.B = Bbf; P.bias = bias;

  pack_all_kernel<<<10240, 256, 0, stream>>>(P);

  const float* c = (const float*)d_in[2];
  dim3 grid(64, 16);
  lstm_gemm_kernel<<<grid, 256, 0, stream>>>(Abf, Bbf, bias, c, hout, cout);
}